// Round 1
// 978.300 us; speedup vs baseline: 1.0281x; 1.0281x over previous
//
#include <hip/hip_runtime.h>

typedef unsigned short ushort_t;
typedef __attribute__((ext_vector_type(8))) short bf16x8;
typedef __attribute__((ext_vector_type(4))) short bf16x4;
typedef __attribute__((ext_vector_type(4))) float f32x4;

__device__ __forceinline__ unsigned short f2bf(float f) {
  unsigned int u = __float_as_uint(f);
  u += 0x7fffu + ((u >> 16) & 1u);
  return (unsigned short)(u >> 16);
}

__device__ __forceinline__ f32x4 mfma16(bf16x8 a, bf16x8 b, f32x4 c) {
  return __builtin_amdgcn_mfma_f32_16x16x32_bf16(a, b, c, 0, 0, 0);
}

// ---------------- merged f32 -> bf16 convert (4-wide, all 5 tensors) -------
// quad segments: roi 524288 | q_w 262144 | k_w 262144 | conv_w 262144 | pos_w 256
__global__ __launch_bounds__(256) void cvt_all_kernel(
    const float* __restrict__ roi, const float* __restrict__ qw,
    const float* __restrict__ kw, const float* __restrict__ cw,
    const float* __restrict__ pw, ushort_t* __restrict__ rfb,
    ushort_t* __restrict__ qwb, ushort_t* __restrict__ kwb,
    ushort_t* __restrict__ cwb, ushort_t* __restrict__ poswb) {
  int i = blockIdx.x * 256 + threadIdx.x;  // quad index
  const float* s;
  ushort_t* d;
  int off;
  if (i < 524288)       { s = roi; d = rfb;   off = i; }
  else if (i < 786432)  { s = qw;  d = qwb;   off = i - 524288; }
  else if (i < 1048576) { s = kw;  d = kwb;   off = i - 786432; }
  else if (i < 1310720) { s = cw;  d = cwb;   off = i - 1048576; }
  else if (i < 1310976) { s = pw;  d = poswb; off = i - 1310720; }
  else return;
  f32x4 v = *(const f32x4*)(s + (long)off * 4);
  bf16x4 o;
#pragma unroll
  for (int j = 0; j < 4; ++j) o[j] = (short)f2bf(v[j]);
  *(bf16x4*)(d + (long)off * 4) = o;
}

// ---------------- fused Q/K projection: C = A @ W^T + b (bf16 out) ---------
// grid (64, 32, 2): z=0 -> Q, z=1 -> K. A = rfb (2048 x 1024), K compile-time.
__global__ __launch_bounds__(256) void qk_gemm(
    const ushort_t* __restrict__ A, const ushort_t* __restrict__ Wq,
    const ushort_t* __restrict__ Wk, const float* __restrict__ qb,
    const float* __restrict__ kb, ushort_t* __restrict__ Qo,
    ushort_t* __restrict__ Ko) {
  int wave = threadIdx.x >> 6, lane = threadIdx.x & 63;
  int la = lane & 15, qd = lane >> 4;
  const ushort_t* B = blockIdx.z ? Wk : Wq;
  const float* bias = blockIdx.z ? kb : qb;
  ushort_t* C = blockIdx.z ? Ko : Qo;
  int row0 = blockIdx.y * 64 + wave * 16;
  int col0 = blockIdx.x * 16;
  const ushort_t* ar = A + (long)(row0 + la) * 1024 + qd * 8;
  const ushort_t* br = B + (long)(col0 + la) * 1024 + qd * 8;
  f32x4 acc = {0.f, 0.f, 0.f, 0.f};
#pragma unroll 8
  for (int k = 0; k < 1024; k += 32) {
    bf16x8 av = *(const bf16x8*)(ar + k);
    bf16x8 bv = *(const bf16x8*)(br + k);
    acc = mfma16(av, bv, acc);
  }
  int crow = row0 + qd * 4, ccol = col0 + la;
  float bb = bias[ccol];
#pragma unroll
  for (int j = 0; j < 4; ++j)
    C[(long)(crow + j) * 1024 + ccol] = f2bf(acc[j] + bb);
}

// ---------------- generic C = scale*(A @ B^T) + bias (bf16 out) ------------
__global__ __launch_bounds__(256) void gemm_bt(
    const ushort_t* __restrict__ A, const ushort_t* __restrict__ B,
    void* __restrict__ Cv, const float* __restrict__ bias,
    int lda, int ldb, int ldc,
    long sAb, long sAg, long sBb, long sBg, long sCb, long sCg,
    int K, float scale, int c_bf16) {
  int wave = threadIdx.x >> 6, lane = threadIdx.x & 63;
  int la = lane & 15, qd = lane >> 4;
  int z = blockIdx.z, b = z >> 4, g = z & 15;
  const ushort_t* Az = A + (long)b * sAb + (long)g * sAg;
  const ushort_t* Bz = B + (long)b * sBb + (long)g * sBg;
  int row0 = blockIdx.y * 64 + wave * 16;
  int col0 = blockIdx.x * 16;
  const ushort_t* ar = Az + (long)(row0 + la) * lda + qd * 8;
  const ushort_t* br = Bz + (long)(col0 + la) * ldb + qd * 8;
  f32x4 acc = {0.f, 0.f, 0.f, 0.f};
  for (int k = 0; k < K; k += 32) {
    bf16x8 av = *(const bf16x8*)(ar + k);
    bf16x8 bv = *(const bf16x8*)(br + k);
    acc = mfma16(av, bv, acc);
  }
  int crow = row0 + qd * 4, ccol = col0 + la;
  float bb = bias ? bias[ccol] : 0.f;
  long cbase = (long)b * sCb + (long)g * sCg;
#pragma unroll
  for (int j = 0; j < 4; ++j) {
    float v = acc[j] * scale + bb;
    long addr = cbase + (long)(crow + j) * ldc + ccol;
    if (c_bf16) ((ushort_t*)Cv)[addr] = f2bf(v);
    else ((float*)Cv)[addr] = v;
  }
}

// ---------------- fused flash attention over the S path ----------------
// Block: 1024 threads = 16 waves, wave = group g. One block per (b, 8 n-rows).
// Loop m in steps of 32: stage pe->LDS bf16, W = log(max(pe.pos_w+pos_b,eps))
// via MFMA into LDS f32, S = QK^T/8 + W via MFMA, online softmax, P->LDS
// transpose (wave-local), PV against V2T.
// Changes vs prev: (1) pe prefetch issued AFTER bar2 so the barrier's
// vmcnt(0) drain no longer swallows the whole compute section; (2) V loads
// moved after softmax to keep peak VGPR pressure below the 128 cap (1024-thr
// block) and avoid scratch spills.
__global__ __launch_bounds__(1024, 4) void flash_kernel(
    const float* __restrict__ pe, const ushort_t* __restrict__ poswb,
    const float* __restrict__ pos_b, const ushort_t* __restrict__ Qb,
    const ushort_t* __restrict__ Kb, const ushort_t* __restrict__ V2T,
    const float* __restrict__ conv_b, float* __restrict__ out) {
  __shared__ ushort_t peb[256 * 72];      // [nm=n_l*32+m_l][72 (pad)] bf16
  __shared__ float    wlog[256 * 17];     // [nm][17 (pad)] f32
  __shared__ ushort_t ptrb[16][8 * 32];   // per-wave P^T buffer [row][32]

  int tid = threadIdx.x;
  int wave = tid >> 6, lane = tid & 63;
  int la = lane & 15, qd = lane >> 4;
  int g = wave;
  int bx = blockIdx.x;
  int b = bx & 1, nt = bx >> 1;     // b per XCD parity: L2 holds one batch
  int n0 = nt * 8;

  // q A-frags (rows la: n = n0 + (la&7), duplicated for la>=8)
  const ushort_t* qptr =
      Qb + (((long)(b * 1024 + n0 + (la & 7))) << 10) + g * 64 + qd * 8;
  bf16x8 aq0 = *(const bf16x8*)qptr;
  bf16x8 aq1 = *(const bf16x8*)(qptr + 32);
  // pos_w B-frags (rows = g = la)
  const ushort_t* pwp = poswb + la * 64 + qd * 8;
  bf16x8 pw0 = *(const bf16x8*)pwp;
  bf16x8 pw1 = *(const bf16x8*)(pwp + 32);
  float pb_la = pos_b[la];

  // pe staging indices: each lane loads 16 f32 (one n-row chunk of 8KB per
  // 128 lanes), writes 16 bf16 to peb.
  int n_l = tid >> 7, rr = tid & 127;
  int m_l = rr >> 2, e0 = (rr & 3) * 16;
  const float* psrc =
      pe + (((long)(b * 1024 + n0 + n_l) << 10) + m_l) * 64 + e0;
  int pebidx = (n_l * 32 + m_l) * 72 + e0;

  f32x4 O0 = {0,0,0,0}, O1 = {0,0,0,0}, O2 = {0,0,0,0}, O3 = {0,0,0,0};
  float m_i[4], l_i[4];
#pragma unroll
  for (int j = 0; j < 4; ++j) { m_i[j] = -1e30f; l_i[j] = 0.f; }

  f32x4 p0 = *(const f32x4*)(psrc);
  f32x4 p1 = *(const f32x4*)(psrc + 4);
  f32x4 p2 = *(const f32x4*)(psrc + 8);
  f32x4 p3 = *(const f32x4*)(psrc + 12);

  for (int t = 0; t < 32; ++t) {
    // ---- stage pe tile (bf16) ----
    bf16x8 c0, c1;
#pragma unroll
    for (int j = 0; j < 4; ++j) {
      c0[j] = (short)f2bf(p0[j]); c0[j + 4] = (short)f2bf(p1[j]);
      c1[j] = (short)f2bf(p2[j]); c1[j + 4] = (short)f2bf(p3[j]);
    }
    *(bf16x8*)&peb[pebidx] = c0;
    *(bf16x8*)&peb[pebidx + 8] = c1;
    __syncthreads();                       // bar1: peb ready
    // ---- W-GEMM: 256 (n,m)-rows x 16 g, wave w does rows w*16..+15 ----
    const ushort_t* pa = &peb[(wave * 16 + la) * 72 + qd * 8];
    bf16x8 wa0 = *(const bf16x8*)pa;
    bf16x8 wa1 = *(const bf16x8*)(pa + 32);
    f32x4 wacc = {0.f, 0.f, 0.f, 0.f};
    wacc = mfma16(wa0, pw0, wacc);
    wacc = mfma16(wa1, pw1, wacc);
    int wrow = wave * 16 + qd * 4;
#pragma unroll
    for (int j = 0; j < 4; ++j)
      wlog[(wrow + j) * 17 + la] = __logf(fmaxf(wacc[j] + pb_la, 1e-6f));
    __syncthreads();                       // bar2: wlog ready
    // ---- prefetch next pe tile (issued AFTER bar2: the barrier's implicit
    //      vmcnt(0) drain no longer stalls on it; covered by QK+softmax+PV)
    if (t < 31) {
      const float* ps = psrc + (t + 1) * 2048;
      p0 = *(const f32x4*)(ps);
      p1 = *(const f32x4*)(ps + 4);
      p2 = *(const f32x4*)(ps + 8);
      p3 = *(const f32x4*)(ps + 12);
    }
    // ---- S = QK^T/8 + wlog ----
    int m0 = t * 32;
    const ushort_t* kbase =
        Kb + (((long)(b * 1024 + m0)) << 10) + g * 64 + qd * 8;
    bf16x8 kb0 = *(const bf16x8*)(kbase + (long)la * 1024);
    bf16x8 kb1 = *(const bf16x8*)(kbase + (long)la * 1024 + 32);
    bf16x8 kb2 = *(const bf16x8*)(kbase + (long)(la + 16) * 1024);
    bf16x8 kb3 = *(const bf16x8*)(kbase + (long)(la + 16) * 1024 + 32);
    f32x4 s0 = {0.f, 0.f, 0.f, 0.f}, s1 = {0.f, 0.f, 0.f, 0.f};
    s0 = mfma16(aq0, kb0, s0); s0 = mfma16(aq1, kb1, s0);
    s1 = mfma16(aq0, kb2, s1); s1 = mfma16(aq1, kb3, s1);
    // ---- online softmax (rows = n, duplicated for rows>=8) ----
#pragma unroll
    for (int j = 0; j < 4; ++j) {
      int nl = (qd * 4 + j) & 7;
      float sv0 = s0[j] * 0.125f + wlog[(nl * 32 + la) * 17 + g];
      float sv1 = s1[j] * 0.125f + wlog[(nl * 32 + la + 16) * 17 + g];
      float mrow = fmaxf(sv0, sv1);
      mrow = fmaxf(mrow, __shfl_xor(mrow, 1));
      mrow = fmaxf(mrow, __shfl_xor(mrow, 2));
      mrow = fmaxf(mrow, __shfl_xor(mrow, 4));
      mrow = fmaxf(mrow, __shfl_xor(mrow, 8));
      float mn = fmaxf(m_i[j], mrow);
      float alpha = __expf(m_i[j] - mn);
      m_i[j] = mn;
      float e0v = __expf(sv0 - mn), e1v = __expf(sv1 - mn);
      float ps = e0v + e1v;
      ps += __shfl_xor(ps, 1); ps += __shfl_xor(ps, 2);
      ps += __shfl_xor(ps, 4); ps += __shfl_xor(ps, 8);
      l_i[j] = l_i[j] * alpha + ps;
      O0[j] *= alpha; O1[j] *= alpha; O2[j] *= alpha; O3[j] *= alpha;
      if (qd < 2) {                       // store P rows 0..7 (real rows)
        int row = qd * 4 + j;
        ptrb[wave][row * 32 + la] = f2bf(e0v);
        ptrb[wave][row * 32 + la + 16] = f2bf(e1v);
      }
    }
    // ---- V loads (moved post-softmax: peak VGPR pressure < 128, no spill)
    const ushort_t* vb = V2T + ((long)(b * 16 + g) << 16) + m0 + qd * 8;
    bf16x8 v0 = *(const bf16x8*)(vb + (long)la * 1024);
    bf16x8 v1 = *(const bf16x8*)(vb + (long)(16 + la) * 1024);
    bf16x8 v2 = *(const bf16x8*)(vb + (long)(32 + la) * 1024);
    bf16x8 v3 = *(const bf16x8*)(vb + (long)(48 + la) * 1024);
    // ---- PV: A = P^T from wave-local LDS (no block barrier needed) ----
    bf16x8 pA = *(const bf16x8*)&ptrb[wave][(la & 7) * 32 + qd * 8];
    O0 = mfma16(pA, v0, O0);
    O1 = mfma16(pA, v1, O1);
    O2 = mfma16(pA, v2, O2);
    O3 = mfma16(pA, v3, O3);
  }

  // ---- epilogue: rows 0..7 real ----
  if (qd < 2) {
    float* ob = out + (((long)(b * 1024 + n0)) << 10) + g * 64 + la;
    const float* cb = conv_b + g * 64 + la;
#pragma unroll
    for (int j = 0; j < 4; ++j) {
      int row = qd * 4 + j;
      float il = 1.0f / l_i[j];
      float* orow = ob + ((long)row << 10);
      orow[0]  = O0[j] * il + cb[0];
      orow[16] = O1[j] * il + cb[16];
      orow[32] = O2[j] * il + cb[32];
      orow[48] = O3[j] * il + cb[48];
    }
  }
}

extern "C" void kernel_launch(void* const* d_in, const int* in_sizes, int n_in,
                              void* d_out, int out_size, void* d_ws, size_t ws_size,
                              hipStream_t stream) {
  const float* roi_feat = (const float*)d_in[0];   // (2,1024,1024)
  const float* pe       = (const float*)d_in[1];   // (2,1024,1024,64)
  const float* pos_w    = (const float*)d_in[2];   // (16,64)
  const float* pos_b    = (const float*)d_in[3];   // (16)
  const float* q_w      = (const float*)d_in[4];   // (1024,1024)
  const float* q_b      = (const float*)d_in[5];   // (1024)
  const float* k_w      = (const float*)d_in[6];
  const float* k_b      = (const float*)d_in[7];
  const float* conv_w   = (const float*)d_in[8];
  const float* conv_b   = (const float*)d_in[9];
  float* out = (float*)d_out;

  char* w = (char*)d_ws;
  ushort_t* rfb   = (ushort_t*)w; w += (size_t)4 << 20;
  ushort_t* qwb   = (ushort_t*)w; w += (size_t)2 << 20;
  ushort_t* kwb   = (ushort_t*)w; w += (size_t)2 << 20;
  ushort_t* cwb   = (ushort_t*)w; w += (size_t)2 << 20;
  ushort_t* poswb = (ushort_t*)w; w += (size_t)1 << 12;
  ushort_t* Qb    = (ushort_t*)w; w += (size_t)4 << 20;
  ushort_t* Kb    = (ushort_t*)w; w += (size_t)4 << 20;
  ushort_t* V2T   = (ushort_t*)w; w += (size_t)4 << 20;

  // one merged convert (roi, q_w, k_w, conv_w, pos_w)
  cvt_all_kernel<<<5121, 256, 0, stream>>>(
      roi_feat, q_w, k_w, conv_w, pos_w, rfb, qwb, kwb, cwb, poswb);

  // Q = roi @ q_w^T + q_b ; K = roi @ k_w^T + k_b  (bf16, fused launch)
  qk_gemm<<<dim3(64, 32, 2), 256, 0, stream>>>(
      rfb, qwb, kwb, q_b, k_b, Qb, Kb);

  // V2T[b,g][o][m] = cw_g . roi_b^T  (bf16)
  gemm_bt<<<dim3(64, 1, 32), 256, 0, stream>>>(
      cwb, rfb, V2T, (const float*)nullptr, 1024, 1024, 1024,
      0, 65536, 1048576, 0, 1048576, 65536, 1024, 1.f, 1);

  // fused S path: W-bias + QK^T + online softmax + PV
  flash_kernel<<<256, 1024, 0, stream>>>(
      pe, poswb, pos_b, Qb, Kb, V2T, conv_b, out);
}